// Round 10
// baseline (301.976 us; speedup 1.0000x reference)
//
#include <hip/hip_runtime.h>

// Species-routed expert Linear as a bucketed grouped GEMM.
//   out[a] = rho[a] @ W[sym[a]] + b[sym[a]]   (NTA=65536, K=N=512, 4 species)
// R10: persistent multi-tile blocks for CONTINUOUS memory/compute overlap.
//      256 blocks x 1024 threads (1 block/CU, 16 waves). Each block handles
//      ~4 tiles (64 rows x N=512 x K=512) of one species, grid-stride 64.
//      Cross-tile double-buffered LDS (2 x 64 KB): tile t+1's gather is in
//      flight during tile t's MFMA phase; stores fire-and-forget under the
//      next tile. R6's proven 0-conflict LDS layout and store shape.

#define NTA   65536
#define DIM_O 512
#define NMAXD 512
#define NSPE  4

typedef __attribute__((ext_vector_type(4))) float  f32x4;
typedef __attribute__((ext_vector_type(8))) short  bf16x8;
typedef __attribute__((ext_vector_type(4))) short  bf16x4;

__device__ __forceinline__ short f2bf(float f) {
    unsigned u = __builtin_bit_cast(unsigned, f);
    u += 0x7FFFu + ((u >> 16) & 1u);
    return (short)(u >> 16);
}

__global__ void build_lists_kernel(const int* __restrict__ sym,
                                   int* __restrict__ counts,
                                   int* __restrict__ lists) {
    int i = blockIdx.x * 256 + threadIdx.x;
    int s = sym[i];
    int lane = threadIdx.x & 63;
    #pragma unroll
    for (int spe = 0; spe < NSPE; ++spe) {
        unsigned long long m = __ballot(s == spe);
        if (m == 0ull) continue;
        int leader = __ffsll(m) - 1;
        int base = 0;
        if (lane == leader) base = atomicAdd(&counts[spe], __popcll(m));
        base = __shfl(base, leader);
        if (s == spe) {
            int pos = __popcll(m & ((1ull << lane) - 1ull));
            lists[spe * NTA + base + pos] = i;
        }
    }
}

// Pack W[s][k][n] (fp32) -> bf16 MFMA-B fragment layout; also zeroes counts
// (launched BEFORE build_lists on the same stream).
__global__ void pack_w_kernel(const float* __restrict__ W, short* __restrict__ Wp,
                              int* __restrict__ counts) {
    if (blockIdx.x == 0 && threadIdx.x < NSPE) counts[threadIdx.x] = 0;
    int idx = blockIdx.x * 256 + threadIdx.x;
    int j  = idx & 7;
    int l  = (idx >> 3) & 63;
    int nb = (idx >> 9) & 31;
    int kb = (idx >> 14) & 15;
    int s  = idx >> 18;
    int k = kb * 32 + (l >> 4) * 8 + j;
    int n = nb * 16 + (l & 15);
    Wp[idx] = f2bf(W[((size_t)s * DIM_O + k) * NMAXD + n]);
}

// LDS A layout per buffer (full K): 16B slot = c*64 + (row ^ ((c&3)<<1)),
// c = k-chunk of 8 floats (0..63). Measured 0 conflicts (R6/R7).
__global__ __launch_bounds__(1024, 4)
void gemm_kernel(const float* __restrict__ rho,
                 const short* __restrict__ Wp,
                 const float* __restrict__ bias,
                 const int*  __restrict__ counts,
                 const int*  __restrict__ lists,
                 float* __restrict__ out)
{
    const int s = blockIdx.x & 3;          // XCD residue also fixes species
    const int g = blockIdx.x >> 2;         // 0..63
    const int cnt = counts[s];
    const int ntiles = (cnt + 63) >> 6;
    if (g >= ntiles) return;
    const int ntb = min(8, (ntiles - g + 63) >> 6);   // tiles for this block

    __shared__ int aidxm[512];                         // up to 8 tiles x 64 rows
    __shared__ __align__(16) short Abuf[2][64 * 64 * 8];   // 2 x 64 KB

    const int tid  = threadIdx.x;
    const int lane = tid & 63;
    const int w    = tid >> 6;             // wave 0..15 owns cols [w*32, w*32+32)
    const int lrow = lane & 15;
    const int lgr  = lane >> 4;

    // preload ALL this block's row indices (1 barrier, done forever)
    if (tid < ntb * 64) {
        const int t = tid >> 6, r = tid & 63;
        const int idx = (g + t * 64) * 64 + r;
        aidxm[tid] = lists[s * NTA + min(idx, cnt - 1)];
    }
    __syncthreads();

    // staging geometry: 16 threads/row; thread covers 16B at (r*64 + scol16*4)
    // floats; 16 consecutive lanes read 256 B contiguous (requests merge).
    const int srow   = tid >> 4;           // 0..63
    const int scol16 = tid & 15;
    const int c0     = scol16 >> 1;
    const int h      = scol16 & 1;
    const int roww   = srow ^ ((c0 & 3) << 1);

    const short* wbase = Wp + ((size_t)s * 512 + w * 2) * 512 + lane * 8;
    const float bv0 = bias[s * NMAXD + w * 32 + lrow];
    const float bv1 = bias[s * NMAXD + w * 32 + 16 + lrow];

    f32x4 st[8];

    // prologue: gather tile 0 -> LDS0
    {
        const float* gsrc = rho + (size_t)aidxm[srow] * DIM_O + scol16 * 4;
        #pragma unroll
        for (int r = 0; r < 8; ++r) st[r] = *(const f32x4*)(gsrc + r * 64);
        #pragma unroll
        for (int r = 0; r < 8; ++r) {
            bf16x4 a;
            #pragma unroll
            for (int q = 0; q < 4; ++q) a[q] = f2bf(st[r][q]);
            *(bf16x4*)&Abuf[0][((r * 8 + c0) * 64 + roww) * 8 + h * 4] = a;
        }
    }
    __syncthreads();

    for (int t = 0; t < ntb; ++t) {
        const int buf = t & 1;
        const bool hn = (t + 1 < ntb);

        // issue next tile's gather EARLY: latency hides under this tile's MFMAs
        if (hn) {
            const float* gsrc =
                rho + (size_t)aidxm[(t + 1) * 64 + srow] * DIM_O + scol16 * 4;
            #pragma unroll
            for (int r = 0; r < 8; ++r) st[r] = *(const f32x4*)(gsrc + r * 64);
        }

        f32x4 acc[4][2];
        #pragma unroll
        for (int m = 0; m < 4; ++m) { acc[m][0] = (f32x4)0.0f; acc[m][1] = (f32x4)0.0f; }

        #pragma unroll
        for (int kb = 0; kb < 16; ++kb) {
            const bf16x8 bf0 = *(const bf16x8*)(wbase + (size_t)(kb * 32    ) * 512);
            const bf16x8 bf1 = *(const bf16x8*)(wbase + (size_t)(kb * 32 + 1) * 512);
            #pragma unroll
            for (int mf = 0; mf < 4; ++mf) {
                const int c = kb * 4 + lgr;
                const int r = (mf * 16 + lrow) ^ (lgr << 1);
                const bf16x8 afrag = *(const bf16x8*)&Abuf[buf][(c * 64 + r) * 8];
                acc[mf][0] = __builtin_amdgcn_mfma_f32_16x16x32_bf16(
                    afrag, bf0, acc[mf][0], 0, 0, 0);
                acc[mf][1] = __builtin_amdgcn_mfma_f32_16x16x32_bf16(
                    afrag, bf1, acc[mf][1], 0, 0, 0);
            }
        }

        // stores: fire-and-forget, overlap next tile's compute
        const int rbase = (g + t * 64) * 64;
        #pragma unroll
        for (int mf = 0; mf < 4; ++mf) {
            #pragma unroll
            for (int q = 0; q < 4; ++q) {
                const int r = mf * 16 + lgr * 4 + q;
                if (rbase + r < cnt) {
                    float* orow = out + (size_t)aidxm[t * 64 + r] * NMAXD + w * 32 + lrow;
                    orow[0]  = acc[mf][0][q] + bv0;
                    orow[16] = acc[mf][1][q] + bv1;
                }
            }
        }

        if (hn) {
            // convert + write next tile into the other LDS buffer
            #pragma unroll
            for (int r = 0; r < 8; ++r) {
                bf16x4 a;
                #pragma unroll
                for (int q = 0; q < 4; ++q) a[q] = f2bf(st[r][q]);
                *(bf16x4*)&Abuf[buf ^ 1][((r * 8 + c0) * 64 + roww) * 8 + h * 4] = a;
            }
            __syncthreads();
        }
    }
}

extern "C" void kernel_launch(void* const* d_in, const int* in_sizes, int n_in,
                              void* d_out, int out_size, void* d_ws, size_t ws_size,
                              hipStream_t stream) {
    const float* rho = (const float*)d_in[0];
    const float* W   = (const float*)d_in[1];
    const float* b   = (const float*)d_in[2];
    const int*   sym = (const int*)d_in[3];
    float* out = (float*)d_out;

    int*   counts = (int*)d_ws;
    int*   lists  = (int*)((char*)d_ws + 1024);
    short* Wp     = (short*)((char*)d_ws + 1024 + (size_t)NSPE * NTA * 4);

    pack_w_kernel<<<(NSPE * DIM_O * NMAXD) / 256, 256, 0, stream>>>(W, Wp, counts);
    build_lists_kernel<<<NTA / 256, 256, 0, stream>>>(sym, counts, lists);
    gemm_kernel<<<NSPE * 64, 1024, 0, stream>>>(rho, Wp, b, counts, lists, out);
}

// Round 11
// 134.361 us; speedup vs baseline: 2.2475x; 2.2475x over previous
//
#include <hip/hip_runtime.h>

// Species-routed expert Linear as a bucketed grouped GEMM.
//   out[a] = rho[a] @ W[sym[a]] + b[sym[a]]   (NTA=65536, K=N=512, 4 species)
// R11: R6's proven per-tile structure (full-K 64KB A-LDS, barrier-free K-loop,
//      wave-owned 256B store segments) wrapped in a PERSISTENT CHAIN pipeline:
//      grid=256, block b handles tiles b, b+256, ... For each tile, the NEXT
//      tile's 128KB gather is issued into registers BEFORE the K-loop and
//      rides under compute+stores (lgkmcnt-only barriers; counted vmcnt).
//      Removes R6's phase-serial [gather | compute | store] bus idling.

#define NTA   65536
#define DIM_O 512
#define NMAXD 512
#define NSPE  4

typedef __attribute__((ext_vector_type(4))) float  f32x4;
typedef __attribute__((ext_vector_type(8))) short  bf16x8;
typedef __attribute__((ext_vector_type(4))) short  bf16x4;

__device__ __forceinline__ short f2bf(float f) {
    unsigned u = __builtin_bit_cast(unsigned, f);
    u += 0x7FFFu + ((u >> 16) & 1u);
    return (short)(u >> 16);
}

// LDS-visibility barrier that does NOT drain vmcnt (gathers/stores keep flying)
__device__ __forceinline__ void bar_lds() {
    asm volatile("s_waitcnt lgkmcnt(0)" ::: "memory");
    __builtin_amdgcn_s_barrier();
    __builtin_amdgcn_sched_barrier(0);
}

__global__ void build_lists_kernel(const int* __restrict__ sym,
                                   int* __restrict__ counts,
                                   int* __restrict__ lists) {
    int i = blockIdx.x * 256 + threadIdx.x;
    int s = sym[i];
    int lane = threadIdx.x & 63;
    #pragma unroll
    for (int spe = 0; spe < NSPE; ++spe) {
        unsigned long long m = __ballot(s == spe);
        if (m == 0ull) continue;
        int leader = __ffsll(m) - 1;
        int base = 0;
        if (lane == leader) base = atomicAdd(&counts[spe], __popcll(m));
        base = __shfl(base, leader);
        if (s == spe) {
            int pos = __popcll(m & ((1ull << lane) - 1ull));
            lists[spe * NTA + base + pos] = i;
        }
    }
}

// Pack W[s][k][n] (fp32) -> bf16 MFMA-B fragment layout; also zeroes counts
// (launched BEFORE build_lists on the same stream).
__global__ void pack_w_kernel(const float* __restrict__ W, short* __restrict__ Wp,
                              int* __restrict__ counts) {
    if (blockIdx.x == 0 && threadIdx.x < NSPE) counts[threadIdx.x] = 0;
    int idx = blockIdx.x * 256 + threadIdx.x;
    int j  = idx & 7;
    int l  = (idx >> 3) & 63;
    int nb = (idx >> 9) & 31;
    int kb = (idx >> 14) & 15;
    int s  = idx >> 18;
    int k = kb * 32 + (l >> 4) * 8 + j;
    int n = nb * 16 + (l & 15);
    Wp[idx] = f2bf(W[((size_t)s * DIM_O + k) * NMAXD + n]);
}

// LDS A layout (full K): 16B slot = c*64 + (row ^ ((c&3)<<1)), c = k-chunk of
// 8 floats (0..63). Proven 0-conflict both sides (R6/R7).
__global__ __launch_bounds__(512, 2)
void gemm_kernel(const float* __restrict__ rho,
                 const short* __restrict__ Wp,
                 const float* __restrict__ bias,
                 const int*  __restrict__ counts,
                 const int*  __restrict__ lists,
                 float* __restrict__ out)
{
    const int b   = blockIdx.x;          // 0..255, persistent chain id
    const int tid = threadIdx.x;
    const int lane = tid & 63;
    const int w    = tid >> 6;           // wave 0..7 owns cols [w*64, w*64+64)
    const int lrow = lane & 15;
    const int lgr  = lane >> 4;

    // species tile partition (uniform arithmetic)
    const int c0x = counts[0], c1x = counts[1], c2x = counts[2], c3x = counts[3];
    const int P1 = (c0x + 63) >> 6;
    const int P2 = P1 + ((c1x + 63) >> 6);
    const int P3 = P2 + ((c2x + 63) >> 6);
    const int ntot = P3 + ((c3x + 63) >> 6);

    __shared__ int aidxA[2][64];
    __shared__ __align__(16) short Abuf[64 * 64 * 8];   // 64 KB

    // staging geometry (R6): thread t -> row t>>3, 8 lanes = 128B contiguous
    const int srow  = tid >> 3;
    const int scol8 = tid & 7;
    const int cc0   = scol8 >> 1;
    const int roww  = srow ^ ((cc0 & 3) << 1);
    const int dof   = (scol8 & 1) * 4;

    #define TILE_INFO(ti, s_, mb_, cnt_)                                   \
        {   s_ = ((ti) >= P1) + ((ti) >= P2) + ((ti) >= P3);               \
            mb_ = (ti) - (s_ == 0 ? 0 : s_ == 1 ? P1 : s_ == 2 ? P2 : P3); \
            cnt_ = (s_ == 0 ? c0x : s_ == 1 ? c1x : s_ == 2 ? c2x : c3x); }

    f32x4 st[16];

    // ---- prologue: aidx + gather for tile b ----
    {
        int s, mb, cnt; TILE_INFO(b, s, mb, cnt);
        if (tid < 64) aidxA[0][tid] = lists[s * NTA + min(mb * 64 + tid, cnt - 1)];
    }
    __syncthreads();
    {
        const float* g = rho + (size_t)aidxA[0][srow] * DIM_O + scol8 * 4;
        #pragma unroll
        for (int r = 0; r < 16; ++r) st[r] = *(const f32x4*)(g + r * 32);
    }

    int p = 0;
    for (int ti = b; ti < ntot; ti += 256, p ^= 1) {
        int s, mb, cnt; TILE_INFO(ti, s, mb, cnt);
        const int rows_here = min(64, cnt - mb * 64);

        bar_lds();   // all prior ABuf reads complete

        // convert in-flight gather (tile ti) -> ABuf  (counted vmcnt wait)
        #pragma unroll
        for (int r = 0; r < 16; ++r) {
            bf16x4 a;
            #pragma unroll
            for (int q = 0; q < 4; ++q) a[q] = f2bf(st[r][q]);
            *(bf16x4*)&Abuf[((r * 4 + cc0) * 64 + roww) * 8 + dof] = a;
        }

        // next tile's row indices
        const int tn = ti + 256;
        if (tn < ntot) {
            int s2, mb2, cnt2; TILE_INFO(tn, s2, mb2, cnt2);
            if (tid < 64)
                aidxA[p ^ 1][tid] = lists[s2 * NTA + min(mb2 * 64 + tid, cnt2 - 1)];
        }
        bar_lds();   // ABuf + aidxA[p^1] visible

        // ISSUE next tile's gather NOW — rides under K-loop + stores
        if (tn < ntot) {
            const float* g = rho + (size_t)aidxA[p ^ 1][srow] * DIM_O + scol8 * 4;
            #pragma unroll
            for (int r = 0; r < 16; ++r) st[r] = *(const f32x4*)(g + r * 32);
        }

        // ---- K-loop (R6, barrier-free): L2-resident B + LDS A + MFMA ----
        const short* wbase = Wp + ((size_t)s * 512 + w * 4) * 512 + lane * 8;

        f32x4 acc[4][4];
        #pragma unroll
        for (int m = 0; m < 4; ++m)
            #pragma unroll
            for (int n = 0; n < 4; ++n) acc[m][n] = (f32x4)0.0f;

        #pragma unroll
        for (int kt = 0; kt < 8; ++kt) {
            bf16x8 bfr[2][4];
            #pragma unroll
            for (int ks = 0; ks < 2; ++ks)
                #pragma unroll
                for (int nf = 0; nf < 4; ++nf)
                    bfr[ks][nf] = *(const bf16x8*)
                        (wbase + (size_t)((kt * 2 + ks) * 32 + nf) * 512);
            #pragma unroll
            for (int ks = 0; ks < 2; ++ks) {
                #pragma unroll
                for (int mf = 0; mf < 4; ++mf) {
                    const int c = kt * 8 + ks * 4 + lgr;
                    const int r = (mf * 16 + lrow) ^ ((lgr & 3) << 1);
                    const bf16x8 afrag = *(const bf16x8*)&Abuf[(c * 64 + r) * 8];
                    #pragma unroll
                    for (int nf = 0; nf < 4; ++nf)
                        acc[mf][nf] = __builtin_amdgcn_mfma_f32_16x16x32_bf16(
                            afrag, bfr[ks][nf], acc[mf][nf], 0, 0, 0);
                }
            }
        }

        // ---- stores (R6 shape: wave-owned 256B segments, full lines) ----
        float bv[4];
        #pragma unroll
        for (int nf = 0; nf < 4; ++nf)
            bv[nf] = bias[s * NMAXD + w * 64 + nf * 16 + lrow];
        #pragma unroll
        for (int mf = 0; mf < 4; ++mf) {
            #pragma unroll
            for (int q = 0; q < 4; ++q) {
                const int r = mf * 16 + lgr * 4 + q;
                if (r < rows_here) {
                    float* orow = out + (size_t)aidxA[p][r] * NMAXD + w * 64 + lrow;
                    #pragma unroll
                    for (int nf = 0; nf < 4; ++nf)
                        orow[nf * 16] = acc[mf][nf][q] + bv[nf];
                }
            }
        }
    }
    #undef TILE_INFO
}

extern "C" void kernel_launch(void* const* d_in, const int* in_sizes, int n_in,
                              void* d_out, int out_size, void* d_ws, size_t ws_size,
                              hipStream_t stream) {
    const float* rho = (const float*)d_in[0];
    const float* W   = (const float*)d_in[1];
    const float* b   = (const float*)d_in[2];
    const int*   sym = (const int*)d_in[3];
    float* out = (float*)d_out;

    int*   counts = (int*)d_ws;
    int*   lists  = (int*)((char*)d_ws + 1024);
    short* Wp     = (short*)((char*)d_ws + 1024 + (size_t)NSPE * NTA * 4);

    pack_w_kernel<<<(NSPE * DIM_O * NMAXD) / 256, 256, 0, stream>>>(W, Wp, counts);
    build_lists_kernel<<<NTA / 256, 256, 0, stream>>>(sym, counts, lists);
    gemm_kernel<<<256, 512, 0, stream>>>(rho, Wp, b, counts, lists, out);
}

// Round 12
// 129.025 us; speedup vs baseline: 2.3404x; 1.0414x over previous
//
#include <hip/hip_runtime.h>

// Species-routed expert Linear as a bucketed grouped GEMM.
//   out[a] = rho[a] @ W[sym[a]] + b[sym[a]]   (NTA=65536, K=N=512, 4 species)
// R12: PRODUCER/CONSUMER WAVE SPECIALIZATION. vmcnt is a per-wave in-order
//      queue; in R6-R11 each wave's random-row gather loads sat in front of
//      its K-loop B-load waits, serializing every "pipeline". Now: 4 producer
//      waves carry ONLY gather loads (gather tile t+1 -> Abuf[p^1]); 8
//      consumer waves carry ONLY B-loads + MFMA + stores (R6's proven K-loop
//      and store shape on Abuf[p]). 2 x 64 KB A double-buffer, one
//      lgkmcnt-only barrier per tile, persistent chains (grid=256, ~4 tiles).

#define NTA   65536
#define DIM_O 512
#define NMAXD 512
#define NSPE  4

typedef __attribute__((ext_vector_type(4))) float  f32x4;
typedef __attribute__((ext_vector_type(8))) short  bf16x8;
typedef __attribute__((ext_vector_type(4))) short  bf16x4;

__device__ __forceinline__ short f2bf(float f) {
    unsigned u = __builtin_bit_cast(unsigned, f);
    u += 0x7FFFu + ((u >> 16) & 1u);
    return (short)(u >> 16);
}

// LDS-visibility barrier that does NOT drain vmcnt (stores/gathers keep flying)
__device__ __forceinline__ void bar_lds() {
    asm volatile("s_waitcnt lgkmcnt(0)" ::: "memory");
    __builtin_amdgcn_s_barrier();
    __builtin_amdgcn_sched_barrier(0);
}

__global__ void build_lists_kernel(const int* __restrict__ sym,
                                   int* __restrict__ counts,
                                   int* __restrict__ lists) {
    int i = blockIdx.x * 256 + threadIdx.x;
    int s = sym[i];
    int lane = threadIdx.x & 63;
    #pragma unroll
    for (int spe = 0; spe < NSPE; ++spe) {
        unsigned long long m = __ballot(s == spe);
        if (m == 0ull) continue;
        int leader = __ffsll(m) - 1;
        int base = 0;
        if (lane == leader) base = atomicAdd(&counts[spe], __popcll(m));
        base = __shfl(base, leader);
        if (s == spe) {
            int pos = __popcll(m & ((1ull << lane) - 1ull));
            lists[spe * NTA + base + pos] = i;
        }
    }
}

// Pack W[s][k][n] (fp32) -> bf16 MFMA-B fragment layout; also zeroes counts
// (launched BEFORE build_lists on the same stream).
__global__ void pack_w_kernel(const float* __restrict__ W, short* __restrict__ Wp,
                              int* __restrict__ counts) {
    if (blockIdx.x == 0 && threadIdx.x < NSPE) counts[threadIdx.x] = 0;
    int idx = blockIdx.x * 256 + threadIdx.x;
    int j  = idx & 7;
    int l  = (idx >> 3) & 63;
    int nb = (idx >> 9) & 31;
    int kb = (idx >> 14) & 15;
    int s  = idx >> 18;
    int k = kb * 32 + (l >> 4) * 8 + j;
    int n = nb * 16 + (l & 15);
    Wp[idx] = f2bf(W[((size_t)s * DIM_O + k) * NMAXD + n]);
}

// LDS A layout per buffer (full K): 16B slot = c*64 + (row ^ ((c&3)<<1)),
// c = k-chunk of 8 floats (0..63). Proven 0-conflict both sides (R6/R7).
__global__ __launch_bounds__(768, 3)
void gemm_kernel(const float* __restrict__ rho,
                 const short* __restrict__ Wp,
                 const float* __restrict__ bias,
                 const int*  __restrict__ counts,
                 const int*  __restrict__ lists,
                 float* __restrict__ out)
{
    const int b    = blockIdx.x;          // 0..255, persistent chain id
    const int tid  = threadIdx.x;
    const int lane = tid & 63;
    const int w    = tid >> 6;            // 0..7 consumers, 8..11 producers

    // species tile partition (uniform arithmetic)
    const int c0x = counts[0], c1x = counts[1], c2x = counts[2], c3x = counts[3];
    const int P1 = (c0x + 63) >> 6;
    const int P2 = P1 + ((c1x + 63) >> 6);
    const int P3 = P2 + ((c2x + 63) >> 6);
    const int ntot = P3 + ((c3x + 63) >> 6);
    if (b >= ntot) return;

    __shared__ int aidx[2][64];
    __shared__ __align__(16) short Abuf[2][64 * 64 * 8];   // 2 x 64 KB

    #define TILE_INFO(ti, s_, mb_, cnt_)                                   \
        {   s_ = ((ti) >= P1) + ((ti) >= P2) + ((ti) >= P3);               \
            mb_ = (ti) - (s_ == 0 ? 0 : s_ == 1 ? P1 : s_ == 2 ? P2 : P3); \
            cnt_ = (s_ == 0 ? c0x : s_ == 1 ? c1x : s_ == 2 ? c2x : c3x); }

    // producer gather geometry (R6 prologue shape, 2 passes of 32 rows):
    // thread pt covers row (pt>>3)+ps*32, floats scol8*4 + r*32 (r=0..15);
    // 8 consecutive lanes read 128 B contiguous (requests merge).
    const int pt    = tid - 512;          // valid for producers
    const int scol8 = pt & 7;
    const int cc0   = scol8 >> 1;
    const int dof   = (scol8 & 1) * 4;

    #define GATHER(ti_, dstp_)                                              \
        {   int s2, mb2, cnt2; TILE_INFO(ti_, s2, mb2, cnt2);               \
            if (w == 8)                                                     \
                aidx[dstp_][lane] =                                         \
                    lists[s2 * NTA + min(mb2 * 64 + lane, cnt2 - 1)];       \
            _Pragma("unroll")                                               \
            for (int ps = 0; ps < 2; ++ps) {                                \
                const int srow = (pt >> 3) + ps * 32;                       \
                const int gi = lists[s2 * NTA + min(mb2 * 64 + srow, cnt2 - 1)]; \
                const float* g = rho + (size_t)gi * DIM_O + scol8 * 4;      \
                f32x4 v[16];                                                \
                _Pragma("unroll")                                           \
                for (int r = 0; r < 16; ++r) v[r] = *(const f32x4*)(g + r * 32); \
                const int roww = srow ^ ((cc0 & 3) << 1);                   \
                short* dstb = Abuf[dstp_];                                  \
                _Pragma("unroll")                                           \
                for (int r = 0; r < 16; ++r) {                              \
                    bf16x4 a;                                               \
                    _Pragma("unroll")                                       \
                    for (int q = 0; q < 4; ++q) a[q] = f2bf(v[r][q]);       \
                    *(bf16x4*)&dstb[((r * 4 + cc0) * 64 + roww) * 8 + dof] = a; \
                }                                                           \
            }                                                               \
        }

    // ---- prologue: producers fill Abuf[0] / aidx[0] for tile b ----
    if (w >= 8) GATHER(b, 0);
    bar_lds();

    int p = 0;
    for (int ti = b; ti < ntot; ti += 256, p ^= 1) {
        if (w < 8) {
            // ---------- consumer: R6 K-loop on Abuf[p] ----------
            int s, mb, cnt; TILE_INFO(ti, s, mb, cnt);
            const int rows_here = min(64, cnt - mb * 64);
            const int lrow = lane & 15;
            const int lgr  = lane >> 4;
            const short* Ab = Abuf[p];
            const short* wbase = Wp + ((size_t)s * 512 + w * 4) * 512 + lane * 8;

            f32x4 acc[4][4];
            #pragma unroll
            for (int m = 0; m < 4; ++m)
                #pragma unroll
                for (int n = 0; n < 4; ++n) acc[m][n] = (f32x4)0.0f;

            #pragma unroll
            for (int kt = 0; kt < 8; ++kt) {
                bf16x8 bfr[2][4];
                #pragma unroll
                for (int ks = 0; ks < 2; ++ks)
                    #pragma unroll
                    for (int nf = 0; nf < 4; ++nf)
                        bfr[ks][nf] = *(const bf16x8*)
                            (wbase + (size_t)((kt * 2 + ks) * 32 + nf) * 512);
                #pragma unroll
                for (int ks = 0; ks < 2; ++ks) {
                    #pragma unroll
                    for (int mf = 0; mf < 4; ++mf) {
                        const int c = kt * 8 + ks * 4 + lgr;
                        const int r = (mf * 16 + lrow) ^ ((lgr & 3) << 1);
                        const bf16x8 afrag = *(const bf16x8*)&Ab[(c * 64 + r) * 8];
                        #pragma unroll
                        for (int nf = 0; nf < 4; ++nf)
                            acc[mf][nf] = __builtin_amdgcn_mfma_f32_16x16x32_bf16(
                                afrag, bfr[ks][nf], acc[mf][nf], 0, 0, 0);
                    }
                }
            }

            float bv[4];
            #pragma unroll
            for (int nf = 0; nf < 4; ++nf)
                bv[nf] = bias[s * NMAXD + w * 64 + nf * 16 + lrow];
            #pragma unroll
            for (int mf = 0; mf < 4; ++mf) {
                #pragma unroll
                for (int q = 0; q < 4; ++q) {
                    const int r = mf * 16 + lgr * 4 + q;
                    if (r < rows_here) {
                        float* orow = out + (size_t)aidx[p][r] * NMAXD + w * 64 + lrow;
                        #pragma unroll
                        for (int nf = 0; nf < 4; ++nf)
                            orow[nf * 16] = acc[mf][nf][q] + bv[nf];
                    }
                }
            }
        } else {
            // ---------- producer: gather tile ti+256 into Abuf[p^1] ----------
            const int tn = ti + 256;
            if (tn < ntot) GATHER(tn, p ^ 1);
        }
        bar_lds();
    }
    #undef GATHER
    #undef TILE_INFO
}

extern "C" void kernel_launch(void* const* d_in, const int* in_sizes, int n_in,
                              void* d_out, int out_size, void* d_ws, size_t ws_size,
                              hipStream_t stream) {
    const float* rho = (const float*)d_in[0];
    const float* W   = (const float*)d_in[1];
    const float* b   = (const float*)d_in[2];
    const int*   sym = (const int*)d_in[3];
    float* out = (float*)d_out;

    int*   counts = (int*)d_ws;
    int*   lists  = (int*)((char*)d_ws + 1024);
    short* Wp     = (short*)((char*)d_ws + 1024 + (size_t)NSPE * NTA * 4);

    pack_w_kernel<<<(NSPE * DIM_O * NMAXD) / 256, 256, 0, stream>>>(W, Wp, counts);
    build_lists_kernel<<<NTA / 256, 256, 0, stream>>>(sym, counts, lists);
    gemm_kernel<<<256, 768, 0, stream>>>(rho, Wp, b, counts, lists, out);
}

// Round 13
// 121.712 us; speedup vs baseline: 2.4811x; 1.0601x over previous
//
#include <hip/hip_runtime.h>

// Species-routed expert Linear as a bucketed grouped GEMM.
//   out[a] = rho[a] @ W[sym[a]] + b[sym[a]]   (NTA=65536, K=N=512, 4 species)
// R13: R7 EXACTLY (full A-tile prologue gather -> 64KB LDS, barrier-free
//      K-loop, LDS-transpose epilogue with 1KB-contiguous row stores) with ONE
//      change: output stores are NON-TEMPORAL. Mechanism (from R5/R9/R11/R12
//      accounting): streaming 131MB through the 32MB write-back L2 pins store
//      retirement to DRAM writeback rate, serializing the write leg behind
//      every wave's B-load waits (in-order vmcnt), AND out evicts rho from
//      the 256MB L3 between graph replays. NT stores bypass the dirty-L2
//      path (full 128B lines via the transpose epilogue) and leave L3 to rho.

#define NTA   65536
#define DIM_O 512
#define NMAXD 512
#define NSPE  4
#define BM    64
#define BK    64

typedef __attribute__((ext_vector_type(4))) float  f32x4;
typedef __attribute__((ext_vector_type(8))) short  bf16x8;
typedef __attribute__((ext_vector_type(4))) short  bf16x4;

__device__ __forceinline__ short f2bf(float f) {
    unsigned u = __builtin_bit_cast(unsigned, f);
    u += 0x7FFFu + ((u >> 16) & 1u);
    return (short)(u >> 16);
}

// LDS-visibility barrier that does NOT drain vmcnt
__device__ __forceinline__ void bar_lds() {
    asm volatile("s_waitcnt lgkmcnt(0)" ::: "memory");
    __builtin_amdgcn_s_barrier();
    __builtin_amdgcn_sched_barrier(0);
}

__global__ void build_lists_kernel(const int* __restrict__ sym,
                                   int* __restrict__ counts,
                                   int* __restrict__ lists) {
    int i = blockIdx.x * 256 + threadIdx.x;
    int s = sym[i];
    int lane = threadIdx.x & 63;
    #pragma unroll
    for (int spe = 0; spe < NSPE; ++spe) {
        unsigned long long m = __ballot(s == spe);
        if (m == 0ull) continue;
        int leader = __ffsll(m) - 1;
        int base = 0;
        if (lane == leader) base = atomicAdd(&counts[spe], __popcll(m));
        base = __shfl(base, leader);
        if (s == spe) {
            int pos = __popcll(m & ((1ull << lane) - 1ull));
            lists[spe * NTA + base + pos] = i;
        }
    }
}

// Pack W[s][k][n] (fp32) -> bf16 MFMA-B fragment layout; also zeroes counts
// (launched BEFORE build_lists on the same stream).
__global__ void pack_w_kernel(const float* __restrict__ W, short* __restrict__ Wp,
                              int* __restrict__ counts) {
    if (blockIdx.x == 0 && threadIdx.x < NSPE) counts[threadIdx.x] = 0;
    int idx = blockIdx.x * 256 + threadIdx.x;
    int j  = idx & 7;
    int l  = (idx >> 3) & 63;
    int nb = (idx >> 9) & 31;
    int kb = (idx >> 14) & 15;
    int s  = idx >> 18;
    int k = kb * 32 + (l >> 4) * 8 + j;
    int n = nb * 16 + (l & 15);
    Wp[idx] = f2bf(W[((size_t)s * DIM_O + k) * NMAXD + n]);
}

// LDS A layout (full K): 16B slot = c*64 + (row ^ ((c&3)<<1)),
// c = k-chunk of 8 floats (0..63). Measured 0 conflicts (R6/R7).
__global__ __launch_bounds__(512, 4)
void gemm_kernel(const float* __restrict__ rho,
                 const short* __restrict__ Wp,
                 const float* __restrict__ bias,
                 const int*  __restrict__ counts,
                 const int*  __restrict__ lists,
                 float* __restrict__ out)
{
    const int s   = blockIdx.x & 3;
    const int mb  = blockIdx.x >> 2;
    const int cnt = counts[s];
    const int row0 = mb * BM;
    if (row0 >= cnt) return;
    int rows_here = cnt - row0; if (rows_here > BM) rows_here = BM;

    __shared__ int aidx[BM];
    __shared__ __align__(16) short Abuf[64 * 64 * 8];   // 64 KB: A tile, then O-transpose

    const int tid  = threadIdx.x;
    const int lane = tid & 63;
    const int w    = tid >> 6;            // wave 0..7 owns cols [w*64, w*64+64)
    const int lrow = lane & 15;
    const int lgr  = lane >> 4;

    if (tid < BM)
        aidx[tid] = lists[s * NTA + row0 + ((tid < rows_here) ? tid : 0)];
    __syncthreads();

    // ---- prologue: gather the WHOLE A tile (once), convert, stage to LDS ----
    {
        const int srow  = tid >> 3;
        const int scol8 = tid & 7;
        const float* gsrc = rho + (size_t)aidx[srow] * DIM_O + scol8 * 4;
        const int c0   = scol8 >> 1;
        const int roww = srow ^ ((c0 & 3) << 1);
        const int dof  = (scol8 & 1) * 4;

        f32x4 v[16];
        #pragma unroll
        for (int r = 0; r < 16; ++r)
            v[r] = *(const f32x4*)(gsrc + r * 32);
        #pragma unroll
        for (int r = 0; r < 16; ++r) {
            bf16x4 a;
            #pragma unroll
            for (int q = 0; q < 4; ++q) a[q] = f2bf(v[r][q]);
            *(bf16x4*)&Abuf[((r * 4 + c0) * 64 + roww) * 8 + dof] = a;
        }
    }
    __syncthreads();

    // ---- barrier-free K-loop: read-only LDS + L2-resident B + MFMA ----
    const short* wbase = Wp + ((size_t)s * 512 + w * 4) * 512 + lane * 8;

    f32x4 acc[4][4];
    #pragma unroll
    for (int m = 0; m < 4; ++m)
        #pragma unroll
        for (int n = 0; n < 4; ++n) acc[m][n] = (f32x4)0.0f;

    #pragma unroll
    for (int kt = 0; kt < 8; ++kt) {
        bf16x8 bfr[2][4];
        #pragma unroll
        for (int ks = 0; ks < 2; ++ks)
            #pragma unroll
            for (int nf = 0; nf < 4; ++nf)
                bfr[ks][nf] = *(const bf16x8*)
                    (wbase + (size_t)((kt * 2 + ks) * 32 + nf) * 512);
        #pragma unroll
        for (int ks = 0; ks < 2; ++ks) {
            #pragma unroll
            for (int mf = 0; mf < 4; ++mf) {
                const int c = kt * 8 + ks * 4 + lgr;
                const int r = (mf * 16 + lrow) ^ ((lgr & 3) << 1);
                const bf16x8 afrag = *(const bf16x8*)&Abuf[(c * 64 + r) * 8];
                #pragma unroll
                for (int nf = 0; nf < 4; ++nf)
                    acc[mf][nf] = __builtin_amdgcn_mfma_f32_16x16x32_bf16(
                        afrag, bfr[ks][nf], acc[mf][nf], 0, 0, 0);
            }
        }
    }

    // ---- epilogue: LDS transpose -> contiguous 1KB NON-TEMPORAL stores ----
    float bv[4];
    #pragma unroll
    for (int nf = 0; nf < 4; ++nf)
        bv[nf] = bias[s * NMAXD + w * 64 + nf * 16 + lrow];

    float* Obuf = (float*)Abuf;   // 32 rows x 512 f32 per pass = 64 KB
    bar_lds();                    // all A-tile LDS reads done before overwrite

    #pragma unroll
    for (int p = 0; p < 2; ++p) {
        // write phase: acc rows [p*32, p*32+32); col-XOR by row -> 2-way max
        #pragma unroll
        for (int m2 = 0; m2 < 2; ++m2) {
            const int mf = p * 2 + m2;
            #pragma unroll
            for (int q = 0; q < 4; ++q) {
                const int rl = m2 * 16 + lgr * 4 + q;          // 0..31
                const int sw = ((rl >> 2) & 3) << 4;
                #pragma unroll
                for (int nf = 0; nf < 4; ++nf) {
                    const int col = w * 64 + nf * 16 + lrow;
                    Obuf[rl * 512 + (col ^ sw)] = acc[mf][nf][q] + bv[nf];
                }
            }
        }
        bar_lds();
        // read+store phase: wave w stores rows [w*4, w*4+4); 1KB contiguous/instr
        #pragma unroll
        for (int rr = 0; rr < 4; ++rr) {
            const int rl = w * 4 + rr;
            const int gr = p * 32 + rl;
            const int sw = ((rl >> 2) & 3) << 4;
            if (gr < rows_here) {
                float* orow = out + (size_t)aidx[gr] * NMAXD;
                #pragma unroll
                for (int h = 0; h < 2; ++h) {
                    const int cd = h * 256 + lane * 4;
                    f32x4 v = *(const f32x4*)&Obuf[rl * 512 + (cd ^ sw)];
                    __builtin_nontemporal_store(v, (f32x4*)&orow[cd]);
                }
            }
        }
        if (p == 0) bar_lds();
    }
}

extern "C" void kernel_launch(void* const* d_in, const int* in_sizes, int n_in,
                              void* d_out, int out_size, void* d_ws, size_t ws_size,
                              hipStream_t stream) {
    const float* rho = (const float*)d_in[0];
    const float* W   = (const float*)d_in[1];
    const float* b   = (const float*)d_in[2];
    const int*   sym = (const int*)d_in[3];
    float* out = (float*)d_out;

    int*   counts = (int*)d_ws;
    int*   lists  = (int*)((char*)d_ws + 1024);
    short* Wp     = (short*)((char*)d_ws + 1024 + (size_t)NSPE * NTA * 4);

    pack_w_kernel<<<(NSPE * DIM_O * NMAXD) / 256, 256, 0, stream>>>(W, Wp, counts);
    build_lists_kernel<<<NTA / 256, 256, 0, stream>>>(sym, counts, lists);
    gemm_kernel<<<NSPE * (NTA / BM), 512, 0, stream>>>(rho, Wp, b, counts, lists, out);
}